// Round 2
// baseline (92.512 us; speedup 1.0000x reference)
//
#include <hip/hip_runtime.h>
#include <stdint.h>

typedef __attribute__((ext_vector_type(8))) short short8;   // bf16x8 MFMA frag (4 VGPR)
typedef __attribute__((ext_vector_type(4))) float f32x4;    // fp32x4 MFMA acc
typedef unsigned short u16;

#define GROUPS 16
#define MROWS  16384
#define NCH    128
#define TILES  4          // m-tiles (64 rows) per block
#define BX     64         // grid.x: 64 * 4 * 64 = 16384 rows

__device__ __forceinline__ u16 f2bf(float f) {
    // fp32 -> bf16 round-to-nearest-even (finite inputs only)
    uint32_t u = __float_as_uint(f);
    u += 0x7FFFu + ((u >> 16) & 1u);
    return (u16)(u >> 16);
}

// ---------------------------------------------------------------------------
// Phase 1: build Qt_bf16[g][c][t] = Q[g][t][c], Q = H_0*H_1*...*H_127.
// Rows of Q evolve independently: q_t <- q_t - (q_t . v_i) v_i with
// v_i = w_i * sqrt(2/(w_i.w_i)). Unchanged from R1 (passing, ~3us).
// ---------------------------------------------------------------------------
__global__ __launch_bounds__(256) void build_q(const float* __restrict__ w,
                                               u16* __restrict__ qt) {
    __shared__ float wt[128 * 128];   // 64 KiB: wt[i][(r + 4i)&127] = v_i[r]
    const int g   = blockIdx.y;
    const int rb  = blockIdx.x;       // 0..7
    const int tid = threadIdx.x;
    const float* wg = w + (size_t)g * NCH * NCH;   // weight[g][r][i]

    const int ci = tid & 127;
    float den = 0.f;
    for (int r = 0; r < 128; r += 4) {
        float a0 = wg[(r + 0) * 128 + ci];
        float a1 = wg[(r + 1) * 128 + ci];
        float a2 = wg[(r + 2) * 128 + ci];
        float a3 = wg[(r + 3) * 128 + ci];
        den += a0 * a0 + a1 * a1 + a2 * a2 + a3 * a3;
    }
    if (tid < 128) wt[tid] = sqrtf(2.0f / den);
    __syncthreads();
    const float scl = wt[ci];
    __syncthreads();

    {
        const int h = tid >> 7;
        for (int p = 0; p < 64; ++p) {
            int r = 2 * p + h;
            wt[ci * 128 + ((r + 4 * ci) & 127)] = wg[r * 128 + ci] * scl;
        }
    }
    __syncthreads();

    const int t = rb * 16 + (tid >> 4);
    const int s = tid & 15;
    float q[8];
#pragma unroll
    for (int u = 0; u < 2; ++u)
#pragma unroll
        for (int e = 0; e < 4; ++e)
            q[u * 4 + e] = (4 * s + 64 * u + e == t) ? 1.0f : 0.0f;

    const f32x4* wt4 = (const f32x4*)wt;
    for (int i = 0; i < 128; ++i) {
        f32x4 v0 = wt4[i * 32 + ((s + 0  + i) & 31)];
        f32x4 v1 = wt4[i * 32 + ((s + 16 + i) & 31)];
        float pa = q[0] * v0.x + q[1] * v0.y + q[2] * v0.z + q[3] * v0.w;
        float pb = q[4] * v1.x + q[5] * v1.y + q[6] * v1.z + q[7] * v1.w;
        pa += pb;
        pa += __shfl_xor(pa, 1);
        pa += __shfl_xor(pa, 2);
        pa += __shfl_xor(pa, 4);
        pa += __shfl_xor(pa, 8);
        q[0] -= pa * v0.x; q[1] -= pa * v0.y; q[2] -= pa * v0.z; q[3] -= pa * v0.w;
        q[4] -= pa * v1.x; q[5] -= pa * v1.y; q[6] -= pa * v1.z; q[7] -= pa * v1.w;
    }

    u16* qg = qt + (size_t)g * NCH * NCH;
#pragma unroll
    for (int u = 0; u < 2; ++u)
#pragma unroll
        for (int e = 0; e < 4; ++e)
            qg[(4 * s + 64 * u + e) * 128 + t] = f2bf(q[u * 4 + e]);
}

// ---------------------------------------------------------------------------
// Phase 2: out[g] = x[g] (16384x128 fp32) * Q[g], bf16 MFMA, no x-LDS.
// Block: 256 threads / 4 waves; wave owns 16 rows x 128 cols per tile.
// Q staged ONCE per block in frag-linear LDS [s16][c][8bf16] (conflict-free);
// x double-buffered in registers (direct global float4 -> cvt -> B-frag);
// mfma(Qfrag, xfrag) so D gives 4 consecutive cols/lane -> float4 stores.
// Loop over 4 tiles with prefetch; zero barriers after the single Q barrier.
// ---------------------------------------------------------------------------
__global__ __launch_bounds__(256) void apply_q(const float* __restrict__ x,
                                               const u16* __restrict__ qt,
                                               float* __restrict__ out) {
    __shared__ __align__(16) u16 qs[16][128][8];   // 32 KiB
    const int g   = blockIdx.y;
    const int bx  = blockIdx.x;
    const int tid = threadIdx.x;
    const int wv  = tid >> 6;
    const int l   = tid & 63;
    const int lr  = l & 15;
    const int lb  = l >> 4;

    const size_t rowbase = (size_t)g * MROWS + (size_t)bx * (64 * TILES);
    // per-lane x/out base: row = wv*16 + lr
    const float* xlane = x   + (rowbase + wv * 16 + lr) * NCH;
    float*       olane = out + (rowbase + wv * 16 + lr) * NCH;

    // issue tile-0 x loads FIRST (HBM latency overlaps Q staging + barrier)
    f32x4 xa[8], xb[8];
#pragma unroll
    for (int kb = 0; kb < 4; ++kb) {
        xa[kb * 2 + 0] = *(const f32x4*)(xlane + kb * 32 + lb * 8);
        xa[kb * 2 + 1] = *(const f32x4*)(xlane + kb * 32 + lb * 8 + 4);
    }

    // stage Q^T into frag-linear LDS: qs[s][c][0..7] = Qt[c][8s..8s+7]
    const u16* qg = qt + (size_t)g * NCH * NCH;
#pragma unroll
    for (int p = 0; p < 8; ++p) {
        int f = tid + 256 * p;
        int c = f & 127;
        int s = f >> 7;
        *(uint4*)(&qs[s][c][0]) = *(const uint4*)(qg + c * 128 + s * 8);
    }
    __syncthreads();

#pragma unroll
    for (int t = 0; t < TILES; ++t) {
        // prefetch next tile's x into the other register buffer
        if (t < TILES - 1) {
#pragma unroll
            for (int kb = 0; kb < 4; ++kb) {
                xb[kb * 2 + 0] = *(const f32x4*)(xlane + (t + 1) * 64 * NCH + kb * 32 + lb * 8);
                xb[kb * 2 + 1] = *(const f32x4*)(xlane + (t + 1) * 64 * NCH + kb * 32 + lb * 8 + 4);
            }
        }

        // convert current tile to bf16 B-frags: lane holds row, k = kb*32+lb*8
        short8 afr[4];
#pragma unroll
        for (int kb = 0; kb < 4; ++kb) {
            f32x4 v0 = xa[kb * 2], v1 = xa[kb * 2 + 1];
            short8 a;
            a[0] = (short)f2bf(v0.x); a[1] = (short)f2bf(v0.y);
            a[2] = (short)f2bf(v0.z); a[3] = (short)f2bf(v0.w);
            a[4] = (short)f2bf(v1.x); a[5] = (short)f2bf(v1.y);
            a[6] = (short)f2bf(v1.z); a[7] = (short)f2bf(v1.w);
            afr[kb] = a;
        }

        f32x4 acc[8];
#pragma unroll
        for (int nt = 0; nt < 8; ++nt) { f32x4 z = {0.f, 0.f, 0.f, 0.f}; acc[nt] = z; }

#pragma unroll
        for (int kb = 0; kb < 4; ++kb) {
            const int s = kb * 4 + lb;     // k-chunk this lane consumes
#pragma unroll
            for (int nt = 0; nt < 8; ++nt) {
                short8 qf = *(const short8*)(&qs[s][nt * 16 + lr][0]);
                // A = Q^T frag (row=c_local), B = x frag (col=m_local)
                // D[c][m]: lane&15 = m_local, (lane>>4)*4+reg = c_local
                acc[nt] = __builtin_amdgcn_mfma_f32_16x16x32_bf16(qf, afr[kb], acc[nt], 0, 0, 0);
            }
        }

        // store: row = wv*16+lr, cols nt*16 + lb*4 .. +3 -> float4
#pragma unroll
        for (int nt = 0; nt < 8; ++nt)
            *(f32x4*)(olane + t * 64 * NCH + nt * 16 + lb * 4) = acc[nt];

        // rotate prefetch buffer (compiler renames; forces waitcnt only at
        // next iteration's cvt, i.e. after stores are issued)
#pragma unroll
        for (int i = 0; i < 8; ++i) xa[i] = xb[i];
    }
}

extern "C" void kernel_launch(void* const* d_in, const int* in_sizes, int n_in,
                              void* d_out, int out_size, void* d_ws, size_t ws_size,
                              hipStream_t stream) {
    const float* x = (const float*)d_in[0];
    const float* w = (const float*)d_in[1];
    float* out = (float*)d_out;
    u16* qtw = (u16*)d_ws;               // Qt bf16: 16*128*128*2 = 512 KiB

    build_q<<<dim3(8, GROUPS), 256, 0, stream>>>(w, qtw);
    apply_q<<<dim3(BX, GROUPS), 256, 0, stream>>>(x, qtw, out);
}

// Round 3
// 89.090 us; speedup vs baseline: 1.0384x; 1.0384x over previous
//
#include <hip/hip_runtime.h>
#include <stdint.h>

typedef __attribute__((ext_vector_type(8))) short short8;   // bf16x8 MFMA frag (4 VGPR)
typedef __attribute__((ext_vector_type(4))) float f32x4;    // fp32x4 MFMA acc
typedef unsigned short u16;

#define GROUPS 16
#define MROWS  16384
#define NCH    128

__device__ __forceinline__ u16 f2bf(float f) {
    // fp32 -> bf16 round-to-nearest-even (finite inputs only)
    uint32_t u = __float_as_uint(f);
    u += 0x7FFFu + ((u >> 16) & 1u);
    return (u16)(u >> 16);
}

// ---------------------------------------------------------------------------
// Phase 1: build Qt_bf16[g][c][t] = Q[g][t][c], Q = H_0*H_1*...*H_127.
// Rows of Q evolve independently: q_t <- q_t - (q_t . v_i) v_i with
// v_i = w_i * sqrt(2/(w_i.w_i)). Unchanged (passing, ~3us).
// ---------------------------------------------------------------------------
__global__ __launch_bounds__(256) void build_q(const float* __restrict__ w,
                                               u16* __restrict__ qt) {
    __shared__ float wt[128 * 128];   // 64 KiB: wt[i][(r + 4i)&127] = v_i[r]
    const int g   = blockIdx.y;
    const int rb  = blockIdx.x;       // 0..7
    const int tid = threadIdx.x;
    const float* wg = w + (size_t)g * NCH * NCH;   // weight[g][r][i]

    const int ci = tid & 127;
    float den = 0.f;
    for (int r = 0; r < 128; r += 4) {
        float a0 = wg[(r + 0) * 128 + ci];
        float a1 = wg[(r + 1) * 128 + ci];
        float a2 = wg[(r + 2) * 128 + ci];
        float a3 = wg[(r + 3) * 128 + ci];
        den += a0 * a0 + a1 * a1 + a2 * a2 + a3 * a3;
    }
    if (tid < 128) wt[tid] = sqrtf(2.0f / den);
    __syncthreads();
    const float scl = wt[ci];
    __syncthreads();

    {
        const int h = tid >> 7;
        for (int p = 0; p < 64; ++p) {
            int r = 2 * p + h;
            wt[ci * 128 + ((r + 4 * ci) & 127)] = wg[r * 128 + ci] * scl;
        }
    }
    __syncthreads();

    const int t = rb * 16 + (tid >> 4);
    const int s = tid & 15;
    float q[8];
#pragma unroll
    for (int u = 0; u < 2; ++u)
#pragma unroll
        for (int e = 0; e < 4; ++e)
            q[u * 4 + e] = (4 * s + 64 * u + e == t) ? 1.0f : 0.0f;

    const f32x4* wt4 = (const f32x4*)wt;
    for (int i = 0; i < 128; ++i) {
        f32x4 v0 = wt4[i * 32 + ((s + 0  + i) & 31)];
        f32x4 v1 = wt4[i * 32 + ((s + 16 + i) & 31)];
        float pa = q[0] * v0.x + q[1] * v0.y + q[2] * v0.z + q[3] * v0.w;
        float pb = q[4] * v1.x + q[5] * v1.y + q[6] * v1.z + q[7] * v1.w;
        pa += pb;
        pa += __shfl_xor(pa, 1);
        pa += __shfl_xor(pa, 2);
        pa += __shfl_xor(pa, 4);
        pa += __shfl_xor(pa, 8);
        q[0] -= pa * v0.x; q[1] -= pa * v0.y; q[2] -= pa * v0.z; q[3] -= pa * v0.w;
        q[4] -= pa * v1.x; q[5] -= pa * v1.y; q[6] -= pa * v1.z; q[7] -= pa * v1.w;
    }

    u16* qg = qt + (size_t)g * NCH * NCH;
#pragma unroll
    for (int u = 0; u < 2; ++u)
#pragma unroll
        for (int e = 0; e < 4; ++e)
            qg[(4 * s + 64 * u + e) * 128 + t] = f2bf(q[u * 4 + e]);
}

// ---------------------------------------------------------------------------
// Phase 2: out[g] = x[g] (16384x128 fp32) * Q[g], bf16 MFMA.
// ONE 64-row tile per block, grid 4096 (16 blocks/CU queued, ~5 resident by
// 32 KiB LDS -> ~20 waves/CU). x loads issue first (in flight across Q-stage
// + barrier); Q in frag-linear LDS (conflict-free); float4 output stores.
// Goal: many short blocks = continuous stream of independent loads per CU.
// ---------------------------------------------------------------------------
__global__ __launch_bounds__(256) void apply_q(const float* __restrict__ x,
                                               const u16* __restrict__ qt,
                                               float* __restrict__ out) {
    __shared__ __align__(16) u16 qs[16][128][8];   // 32 KiB
    const int g   = blockIdx.y;
    const int bx  = blockIdx.x;          // 0..255
    const int tid = threadIdx.x;
    const int wv  = tid >> 6;
    const int l   = tid & 63;
    const int lr  = l & 15;
    const int lb  = l >> 4;

    const size_t rowidx = (size_t)g * MROWS + (size_t)bx * 64 + wv * 16 + lr;
    const float* xlane = x   + rowidx * NCH;
    float*       olane = out + rowidx * NCH;

    // issue x loads FIRST: 8 x 16B/lane, covers this lane's row (all 128 k)
    f32x4 xa[8];
#pragma unroll
    for (int kb = 0; kb < 4; ++kb) {
        xa[kb * 2 + 0] = *(const f32x4*)(xlane + kb * 32 + lb * 8);
        xa[kb * 2 + 1] = *(const f32x4*)(xlane + kb * 32 + lb * 8 + 4);
    }

    // stage Q^T into frag-linear LDS: qs[s][c][0..7] = Qt[c][8s..8s+7]
    const u16* qg = qt + (size_t)g * NCH * NCH;
#pragma unroll
    for (int p = 0; p < 8; ++p) {
        int f = tid + 256 * p;
        int c = f & 127;
        int s = f >> 7;
        *(uint4*)(&qs[s][c][0]) = *(const uint4*)(qg + c * 128 + s * 8);
    }
    __syncthreads();

    // convert to bf16 B-frags: lane holds row (wv*16+lr), k = kb*32+lb*8
    short8 afr[4];
#pragma unroll
    for (int kb = 0; kb < 4; ++kb) {
        f32x4 v0 = xa[kb * 2], v1 = xa[kb * 2 + 1];
        short8 a;
        a[0] = (short)f2bf(v0.x); a[1] = (short)f2bf(v0.y);
        a[2] = (short)f2bf(v0.z); a[3] = (short)f2bf(v0.w);
        a[4] = (short)f2bf(v1.x); a[5] = (short)f2bf(v1.y);
        a[6] = (short)f2bf(v1.z); a[7] = (short)f2bf(v1.w);
        afr[kb] = a;
    }

    f32x4 acc[8];
#pragma unroll
    for (int nt = 0; nt < 8; ++nt) { f32x4 z = {0.f, 0.f, 0.f, 0.f}; acc[nt] = z; }

#pragma unroll
    for (int kb = 0; kb < 4; ++kb) {
        const int s = kb * 4 + lb;       // k-chunk this lane consumes
#pragma unroll
        for (int nt = 0; nt < 8; ++nt) {
            short8 qf = *(const short8*)(&qs[s][nt * 16 + lr][0]);
            // A = Q^T frag (row=c_local), B = x frag (col=m_local)
            // D[c][m]: lane&15 = m_local, (lane>>4)*4+reg = c_local
            acc[nt] = __builtin_amdgcn_mfma_f32_16x16x32_bf16(qf, afr[kb], acc[nt], 0, 0, 0);
        }
    }

    // store: row = wv*16+lr, cols nt*16 + lb*4 .. +3 -> float4
#pragma unroll
    for (int nt = 0; nt < 8; ++nt)
        *(f32x4*)(olane + nt * 16 + lb * 4) = acc[nt];
}

extern "C" void kernel_launch(void* const* d_in, const int* in_sizes, int n_in,
                              void* d_out, int out_size, void* d_ws, size_t ws_size,
                              hipStream_t stream) {
    const float* x = (const float*)d_in[0];
    const float* w = (const float*)d_in[1];
    float* out = (float*)d_out;
    u16* qtw = (u16*)d_ws;               // Qt bf16: 16*128*128*2 = 512 KiB

    build_q<<<dim3(8, GROUPS), 256, 0, stream>>>(w, qtw);
    apply_q<<<dim3(MROWS / 64, GROUPS), 256, 0, stream>>>(x, qtw, out);
}